// Round 2
// baseline (1731.993 us; speedup 1.0000x reference)
//
#include <hip/hip_runtime.h>
#include <stdint.h>

// SingleHeadAttention on MI355X (gfx950). Inputs detected fp32-or-bf16 on
// device; internal compute bf16 MFMA (128x128x32 tiles, m97 structure).
// Pipeline: detect -> convert x -> transpose+convert Wqkv,Wo -> bias->fp32 ->
//   GEMM1 (qkv = x@Wqkv + b) -> transpose V -> GEMM-S (P = exp(q@k^T/32), rowsum)
//   -> GEMM-O (O = P@V / rowsum) -> GEMM2 (out = O@Wo + b, out dtype per flag).

typedef uint16_t u16;
typedef __attribute__((ext_vector_type(8))) __bf16 bf16x8;
typedef __attribute__((ext_vector_type(4))) float f32x4;

__device__ __forceinline__ float bf2f(u16 u) {
  union { float f; uint32_t i; } c; c.i = ((uint32_t)u) << 16; return c.f;
}
__device__ __forceinline__ u16 f2bf(float f) {
  union { float f; uint32_t i; } c; c.f = f;
  uint32_t r = c.i + 0x7fffu + ((c.i >> 16) & 1u);
  return (u16)(r >> 16);
}

__device__ __forceinline__ void gl2lds16(const u16* g, u16* l) {
  __builtin_amdgcn_global_load_lds(
      (const __attribute__((address_space(1))) uint32_t*)g,
      (__attribute__((address_space(3))) uint32_t*)l, 16, 0, 0);
}

#define BM 128
#define BN 128
#define BK 32

// flag[0]=1 if x is fp32, 0 if bf16. flag[1]=0 always (a device-zero).
__global__ void detect_dtype(const u16* __restrict__ x, int* __restrict__ flag) {
  __shared__ int cnt[256];
  const int tid = threadIdx.x;
  int c = 0;
  for (int j = tid; j < 4096; j += 256) {
    // even u16 index: for fp32 data this is the LOW mantissa half (exp bits
    // uniform); for bf16 data a genuine ~N(0,1) value (exp field near 127).
    u16 v = x[(long long)j * 16384];
    int e = (v >> 7) & 0xFF;
    c += (e >= 96 && e < 160) ? 1 : 0;
  }
  cnt[tid] = c;
  __syncthreads();
  for (int s = 128; s > 0; s >>= 1) {
    if (tid < s) cnt[tid] += cnt[tid + s];
    __syncthreads();
  }
  if (tid == 0) { flag[0] = (cnt[0] < 2458) ? 1 : 0; flag[1] = 0; }
}

// n8 chunks of 8 elements; fp32->bf16 convert or straight u16 copy.
__global__ void convert_bf16(const void* __restrict__ in, u16* __restrict__ out,
                             long long n8, const int* __restrict__ flag) {
  const long long c0 = (long long)blockIdx.x * blockDim.x + threadIdx.x;
  const long long stride = (long long)gridDim.x * blockDim.x;
  if (flag[0]) {
    for (long long c = c0; c < n8; c += stride) {
      const float4* p = (const float4*)in + c * 2;
      float4 a = p[0], b = p[1];
      u16 t[8] = {f2bf(a.x), f2bf(a.y), f2bf(a.z), f2bf(a.w),
                  f2bf(b.x), f2bf(b.y), f2bf(b.z), f2bf(b.w)};
      *(uint4*)(out + c * 8) = *(uint4*)t;
    }
  } else {
    for (long long c = c0; c < n8; c += stride)
      *(uint4*)(out + c * 8) = ((const uint4*)in)[c];
  }
}

// biasf[0..3071] = bqkv, biasf[3072..7167] = bo (always fp32 out).
__global__ void convert_bias(const void* __restrict__ bq, const void* __restrict__ bo,
                             float* __restrict__ biasf, const int* __restrict__ flag) {
  const int i = blockIdx.x * blockDim.x + threadIdx.x;
  const bool isf = flag[0] != 0;
  if (i < 3072)
    biasf[i] = isf ? ((const float*)bq)[i] : bf2f(((const u16*)bq)[i]);
  else if (i < 7168) {
    int j = i - 3072;
    biasf[i] = isf ? ((const float*)bo)[j] : bf2f(((const u16*)bo)[j]);
  }
}

// out[c][r] = bf16(in[r][c]); in is fp32 if flag[0] else bf16.
__global__ void transpose_cv(const void* __restrict__ in, u16* __restrict__ out,
                             int ldin, int ldout, long long inZ, long long outZ,
                             const int* __restrict__ flag) {
  __shared__ u16 tile[32][33];
  const bool isf = flag[0] != 0;
  const u16* inb = (const u16*)in + (long long)blockIdx.z * inZ;
  const float* inf = (const float*)in + (long long)blockIdx.z * inZ;
  out += (long long)blockIdx.z * outZ;
  const int c0 = blockIdx.x * 32, r0 = blockIdx.y * 32;
  const int tx = threadIdx.x, ty = threadIdx.y;
#pragma unroll
  for (int j = 0; j < 32; j += 8) {
    long long idx = (long long)(r0 + ty + j) * ldin + c0 + tx;
    tile[ty + j][tx] = isf ? f2bf(inf[idx]) : inb[idx];
  }
  __syncthreads();
#pragma unroll
  for (int j = 0; j < 32; j += 8)
    out[(long long)(c0 + ty + j) * ldout + r0 + tx] = tile[tx][ty + j];
}

// C[m][n] = sum_k A[m][k]*B[n][k]  (A,B,C bf16 unless noted)
// MODE 0: +bias[n], bf16 store
// MODE 1: p = exp(acc*scale), bf16 store, atomicAdd rowsum[m]
// MODE 2: acc / rowsum[m], bf16 store
// MODE 3: +bias[n], store fp32 if flag[0] else bf16
template <int MODE>
__global__ __launch_bounds__(256) void gemm_bt(
    const u16* __restrict__ A, const u16* __restrict__ B, u16* __restrict__ C,
    const float* __restrict__ bias, float* __restrict__ rowsum,
    int K, int lda, int ldb, int ldc,
    long long sA, long long sB, long long sC, int rsStride, float scale,
    const int* __restrict__ flag) {
  __shared__ u16 As[BM * BK];
  __shared__ u16 Bs[BN * BK];
  const int tid = threadIdx.x;
  const int lane = tid & 63;
  const int wid = tid >> 6;
  const int z = blockIdx.z;
  A += (long long)z * sA;
  B += (long long)z * sB;
  const int m0 = blockIdx.y * BM;
  const int n0 = blockIdx.x * BN;
  const int wm = wid >> 1, wn = wid & 1;

  f32x4 acc[4][4] = {};

  const int srow = lane >> 2;
  const int scol = (lane & 3) * 8;
  const u16* a0 = A + (long long)(m0 + wid * 32 + srow) * lda + scol;
  const u16* a1 = a0 + (long long)16 * lda;
  const u16* b0 = B + (long long)(n0 + wid * 32 + srow) * ldb + scol;
  const u16* b1 = b0 + (long long)16 * ldb;
  u16* lA0 = &As[(wid * 32) * BK];
  u16* lA1 = &As[(wid * 32 + 16) * BK];
  u16* lB0 = &Bs[(wid * 32) * BK];
  u16* lB1 = &Bs[(wid * 32 + 16) * BK];

  const int fr = lane & 15;
  const int fk = (lane >> 4) * 8;

  for (int k0 = 0; k0 < K; k0 += BK) {
    gl2lds16(a0 + k0, lA0);
    gl2lds16(a1 + k0, lA1);
    gl2lds16(b0 + k0, lB0);
    gl2lds16(b1 + k0, lB1);
    __syncthreads();
    bf16x8 af[4], bf[4];
#pragma unroll
    for (int mi = 0; mi < 4; mi++)
      af[mi] = *(const bf16x8*)&As[(wm * 64 + mi * 16 + fr) * BK + fk];
#pragma unroll
    for (int ni = 0; ni < 4; ni++)
      bf[ni] = *(const bf16x8*)&Bs[(wn * 64 + ni * 16 + fr) * BK + fk];
#pragma unroll
    for (int mi = 0; mi < 4; mi++)
#pragma unroll
      for (int ni = 0; ni < 4; ni++)
        acc[mi][ni] =
            __builtin_amdgcn_mfma_f32_16x16x32_bf16(af[mi], bf[ni], acc[mi][ni], 0, 0, 0);
    __syncthreads();
  }

  // C/D layout (16x16x32): col = lane&15, row = (lane>>4)*4 + reg.
  const bool isf = (MODE == 3) ? (flag[0] != 0) : false;
  const int er = (lane >> 4) * 4;
  const int ec = lane & 15;
#pragma unroll
  for (int mi = 0; mi < 4; mi++) {
#pragma unroll
    for (int r = 0; r < 4; r++) {
      const int m = m0 + wm * 64 + mi * 16 + er + r;
      float rinv = 0.f, psum = 0.f;
      if (MODE == 2) rinv = 1.0f / rowsum[z * rsStride + m];
#pragma unroll
      for (int ni = 0; ni < 4; ni++) {
        const int n = n0 + wn * 64 + ni * 16 + ec;
        float v = acc[mi][ni][r];
        if (MODE == 0 || MODE == 3) v += bias[n];
        if (MODE == 1) { v = __expf(v * scale); psum += v; }
        if (MODE == 2) v *= rinv;
        const long long ci = (long long)z * sC + (long long)m * ldc + n;
        if (MODE == 3 && isf) ((float*)C)[ci] = v;
        else C[ci] = f2bf(v);
      }
      if (MODE == 1) {
        psum += __shfl_xor(psum, 1, 64);
        psum += __shfl_xor(psum, 2, 64);
        psum += __shfl_xor(psum, 4, 64);
        psum += __shfl_xor(psum, 8, 64);
        if (ec == 0) atomicAdd(&rowsum[z * rsStride + m], psum);
      }
    }
  }
}

extern "C" void kernel_launch(void* const* d_in, const int* in_sizes, int n_in,
                              void* d_out, int out_size, void* d_ws, size_t ws_size,
                              hipStream_t stream) {
  (void)in_sizes; (void)n_in; (void)out_size; (void)ws_size;
  const void* x    = d_in[0];  // (4,4096,4096)
  const void* Wqkv = d_in[1];  // (4096,3072)
  const void* bqkv = d_in[2];  // (3072,)
  const void* Wo   = d_in[3];  // (1024,4096)
  const void* bo   = d_in[4];  // (4096,)

  // workspace (~288 MiB) with aliasing: Pm reuses xbf, Ob reuses qkv.
  char* p = (char*)d_ws;
  u16* xbf   = (u16*)p; p += (size_t)16384 * 4096 * 2;   // also Pm (4,4096,4096)
  u16* qkv   = (u16*)p; p += (size_t)16384 * 3072 * 2;   // also Ob (16384,1024)
  u16* WqkvT = (u16*)p; p += (size_t)3072 * 4096 * 2;
  u16* WoT   = (u16*)p; p += (size_t)4096 * 1024 * 2;
  u16* VT    = (u16*)p; p += (size_t)4 * 1024 * 4096 * 2;
  float* rowsum = (float*)p; p += (size_t)16384 * 4;
  float* biasf  = (float*)p; p += (size_t)7168 * 4;
  int* flag = (int*)p;
  u16* Pm = xbf;
  u16* Ob = qkv;

  detect_dtype<<<1, 256, 0, stream>>>((const u16*)x, flag);
  hipMemsetAsync(rowsum, 0, (size_t)16384 * sizeof(float), stream);

  convert_bf16<<<2048, 256, 0, stream>>>(x, xbf, 67108864LL / 8, flag);
  convert_bias<<<28, 256, 0, stream>>>(bqkv, bo, biasf, flag);
  // Wqkv (4096x3072) -> WqkvT (3072x4096)
  transpose_cv<<<dim3(96, 128, 1), dim3(32, 8), 0, stream>>>(Wqkv, WqkvT, 3072, 4096, 0, 0, flag);
  // Wo (1024x4096) -> WoT (4096,1024)
  transpose_cv<<<dim3(128, 32, 1), dim3(32, 8), 0, stream>>>(Wo, WoT, 4096, 1024, 0, 0, flag);

  // qkv = x @ Wqkv + bqkv : M=16384 N=3072 K=4096
  gemm_bt<0><<<dim3(3072 / BN, 16384 / BM, 1), 256, 0, stream>>>(
      xbf, WqkvT, qkv, biasf, nullptr, 4096, 4096, 4096, 3072, 0, 0, 0, 0, 0.f, nullptr);

  // V (qkv cols 2048..3071, bf16) -> VT (4,1024,4096); flag+1 is a device 0.
  transpose_cv<<<dim3(32, 128, 4), dim3(32, 8), 0, stream>>>(
      qkv + 2048, VT, 3072, 4096, (long long)4096 * 3072, (long long)1024 * 4096, flag + 1);

  // P = exp(q @ k^T / 32), rowsum accum : per batch M=N=4096 K=1024
  gemm_bt<1><<<dim3(4096 / BN, 4096 / BM, 4), 256, 0, stream>>>(
      qkv, qkv + 1024, Pm, nullptr, rowsum, 1024, 3072, 3072, 4096,
      (long long)4096 * 3072, (long long)4096 * 3072, (long long)4096 * 4096, 4096,
      0.03125f, nullptr);

  // O = (P @ V) / rowsum : per batch M=4096 N=1024 K=4096  (Ob aliases qkv)
  gemm_bt<2><<<dim3(1024 / BN, 4096 / BM, 4), 256, 0, stream>>>(
      Pm, VT, Ob, nullptr, rowsum, 4096, 4096, 4096, 1024,
      (long long)4096 * 4096, (long long)4096 * 1024, (long long)4096 * 1024, 4096,
      0.f, nullptr);

  // out = O @ Wo + bo : M=16384 N=4096 K=1024; out dtype per flag
  gemm_bt<3><<<dim3(4096 / BN, 16384 / BM, 1), 256, 0, stream>>>(
      Ob, WoT, (u16*)d_out, biasf + 3072, nullptr, 1024, 1024, 1024, 4096,
      0, 0, 0, 0, 0.f, flag);
}